// Round 2
// baseline (124141.504 us; speedup 1.0000x reference)
//
#include <hip/hip_runtime.h>
#include <math.h>

#define NB 512   // batch
#define NL 256   // seq len
#define NH 512   // hidden
#define NG 2048  // 4*H

// ---------------- ws layout (float offsets) ----------------
#define WT_ENC   ((size_t)0)          // 512*2048  WhhT_enc[k][j]
#define WT_DEC   ((size_t)1048576)    // 512*2048
#define W1T_OFF  ((size_t)2097152)    // 512*512   W1T[k][n]
#define W2T_OFF  ((size_t)2359296)    // 512*512
#define A_ENC    ((size_t)2621440)    // 2048
#define D_ENC    ((size_t)2623488)    // 2048
#define A_DEC    ((size_t)2625536)    // 2048
#define D_DEC    ((size_t)2627584)    // 2048
#define HPING    ((size_t)2629632)    // 512*512
#define HPONG    ((size_t)2891776)    // 512*512
#define CBUF     ((size_t)3153920)    // 512*512
#define PG_OFF   ((size_t)3416064)    // 4*512*2048 split-K gate partials
#define PQ_OFF   ((size_t)7610368)    // 4*512*512  split-K q/ep partials
#define NXT_OFF  ((size_t)8658944)    // 512
#define EP_OFF   ((size_t)8659456)    // 256*512*512  enc_proj [l][b][h]
// total = 75,768,320 floats = 303.1 MB  (was 571.5 MB — suspected ws overflow)

__device__ __forceinline__ float fast_rcp(float x) {
  return __builtin_amdgcn_rcpf(x);
}
__device__ __forceinline__ float fast_tanh(float x) {
  x = fminf(x, 10.0f);                       // avoid inf/inf for large +x
  float t = __expf(2.0f * x);                // e^{2x}
  return 1.0f - 2.0f * fast_rcp(t + 1.0f);
}
__device__ __forceinline__ float fast_sigmoid(float x) {
  return fast_rcp(1.0f + __expf(-x));
}

// ---- generic transpose: src (N rows x K cols) -> dst[k*N + n] ----
__global__ void k_transpose(const float* __restrict__ src, float* __restrict__ dst,
                            int N, int K, int lgN) {
  const int o = blockIdx.x * 256 + threadIdx.x;
  if (o >= N * K) return;
  const int n = o & (N - 1);
  const int k = o >> lgN;
  dst[o] = src[(size_t)n * K + k];
}

// ---- A[j] = Wih[j,:]·embW ; D[j] = Wih[j,:]·embB + bih[j] + bhh[j] ----
__global__ void k_prep_ad(const float* __restrict__ Wih, const float* __restrict__ embW,
                          const float* __restrict__ embB, const float* __restrict__ bih,
                          const float* __restrict__ bhh, float* __restrict__ A,
                          float* __restrict__ D) {
  const int wv = threadIdx.x >> 6, lane = threadIdx.x & 63;
  const int j = blockIdx.x * 4 + wv;  // 512 blocks * 4 waves = 2048
  const float* __restrict__ row = Wih + (size_t)j * NH;
  float a = 0.f, d = 0.f;
#pragma unroll
  for (int r = 0; r < 8; ++r) {
    const int k = lane + 64 * r;
    const float w = row[k];
    a = fmaf(w, embW[k], a);
    d = fmaf(w, embB[k], d);
  }
#pragma unroll
  for (int dd = 1; dd < 64; dd <<= 1) {
    a += __shfl_xor(a, dd, 64);
    d += __shfl_xor(d, dd, 64);
  }
  if (lane == 0) { A[j] = a; D[j] = d + bih[j] + bhh[j]; }
}

__global__ void k_init_nxt(float* __restrict__ nxt) {
  nxt[threadIdx.x] = -1.0f;  // SOS
}

// ---- broadcast-operand split-K GEMM: Pout[kc][b][j] = sum_{k in chunk} h[b][k]*WT[k][j]
// grid (N/64, 8, 4), 64 threads. WT is [k][j] (pre-transposed). h-operand is wave-uniform
// (scalar-load path), weight column lives in 128 VGPRs.
__global__ void k_gemm_part(const float* __restrict__ hsrc, const float* __restrict__ WT,
                            float* __restrict__ Pout, int N) {
  const int j  = blockIdx.x * 64 + threadIdx.x;
  const int bq = blockIdx.y;
  const int kc = blockIdx.z;
  const int k0 = kc * 128;
  float w[128];
#pragma unroll
  for (int kk = 0; kk < 128; ++kk) w[kk] = WT[(size_t)(k0 + kk) * N + j];
  for (int bb = 0; bb < 64; ++bb) {
    const int b = bq * 64 + bb;
    const float* __restrict__ hb = hsrc + (size_t)b * NH + k0;
    float a0 = 0.f, a1 = 0.f, a2 = 0.f, a3 = 0.f;
#pragma unroll
    for (int kk = 0; kk < 128; kk += 4) {
      a0 = fmaf(hb[kk + 0], w[kk + 0], a0);
      a1 = fmaf(hb[kk + 1], w[kk + 1], a1);
      a2 = fmaf(hb[kk + 2], w[kk + 2], a2);
      a3 = fmaf(hb[kk + 3], w[kk + 3], a3);
    }
    Pout[((size_t)kc * NB + b) * N + j] = (a0 + a1) + (a2 + a3);
  }
}

// ---- reduce split-K partials + x*A + D, apply LSTM cell ----
__global__ void k_lstm_post(const float* __restrict__ P, const float* __restrict__ A,
                            const float* __restrict__ D, const float* __restrict__ xs,
                            int xs_stride, float* __restrict__ c, float* __restrict__ hdst) {
  const int b  = blockIdx.y;
  const int jp = blockIdx.x * 256 + threadIdx.x;
  const float x = xs[(size_t)b * xs_stride];
  float g[4];
#pragma unroll
  for (int gg = 0; gg < 4; ++gg) {
    const int j = gg * NH + jp;
    float s = fmaf(x, A[j], D[j]);
    s += P[((size_t)0 * NB + b) * NG + j];
    s += P[((size_t)1 * NB + b) * NG + j];
    s += P[((size_t)2 * NB + b) * NG + j];
    s += P[((size_t)3 * NB + b) * NG + j];
    g[gg] = s;
  }
  const float gi = fast_sigmoid(g[0]);
  const float gf = fast_sigmoid(g[1]);
  const float gg_ = fast_tanh(g[2]);
  const float go = fast_sigmoid(g[3]);
  const int idx = b * NH + jp;
  const float cn = gf * c[idx] + gi * gg_;
  c[idx] = cn;
  hdst[idx] = go * fast_tanh(cn);
}

// ---- reduce 4 split-K partials + bias into ep[t][b][:] ----
__global__ void k_ep_reduce(const float* __restrict__ PQ, const float* __restrict__ w1b,
                            float* __restrict__ ep_t) {
  const int b = blockIdx.x;
  const int tid = threadIdx.x;
#pragma unroll
  for (int r = 0; r < 2; ++r) {
    const int h = tid + 256 * r;
    ep_t[(size_t)b * NH + h] =
        PQ[((size_t)0 * NB + b) * NH + h] + PQ[((size_t)1 * NB + b) * NH + h] +
        PQ[((size_t)2 * NB + b) * NH + h] + PQ[((size_t)3 * NB + b) * NH + h] + w1b[h];
  }
}

// ---- attention step t: q from PQ partials, u = v·tanh(ep+q)+vb, log_softmax, argmax ----
__global__ void k_attn(const float* __restrict__ PQ, const float* __restrict__ w2b,
                       const float* __restrict__ ep, const float* __restrict__ vW,
                       const float* __restrict__ vb, const float* __restrict__ in_seq,
                       float* __restrict__ out_attn, float* __restrict__ out_ptr,
                       float* __restrict__ nxt, int t) {
  __shared__ float qsh[NH];
  __shared__ float ush[NL];
  __shared__ float red[2];
  __shared__ int   pidx;
  const int b = blockIdx.x;
  const int tid = threadIdx.x;
#pragma unroll
  for (int r = 0; r < 2; ++r) {
    const int h = tid + 256 * r;
    qsh[h] = PQ[((size_t)0 * NB + b) * NH + h] + PQ[((size_t)1 * NB + b) * NH + h] +
             PQ[((size_t)2 * NB + b) * NH + h] + PQ[((size_t)3 * NB + b) * NH + h] + w2b[h];
  }
  __syncthreads();
  const int wv = tid >> 6, lane = tid & 63;
  const float4* vW4 = (const float4*)vW;
  const float4 v0 = vW4[lane];
  const float4 v1 = vW4[64 + lane];
  const float4 q0 = *(const float4*)&qsh[4 * lane];
  const float4 q1 = *(const float4*)&qsh[256 + 4 * lane];
  const float vbs = vb[0];
  for (int li = 0; li < 64; ++li) {
    const int l = wv * 64 + li;
    const float4* eprow = (const float4*)(ep + ((size_t)l * NB + b) * NH);
    const float4 e0 = eprow[lane];
    const float4 e1 = eprow[64 + lane];
    float s;
    s = v0.x * fast_tanh(e0.x + q0.x);
    s = fmaf(v0.y, fast_tanh(e0.y + q0.y), s);
    s = fmaf(v0.z, fast_tanh(e0.z + q0.z), s);
    s = fmaf(v0.w, fast_tanh(e0.w + q0.w), s);
    s = fmaf(v1.x, fast_tanh(e1.x + q1.x), s);
    s = fmaf(v1.y, fast_tanh(e1.y + q1.y), s);
    s = fmaf(v1.z, fast_tanh(e1.z + q1.z), s);
    s = fmaf(v1.w, fast_tanh(e1.w + q1.w), s);
#pragma unroll
    for (int d = 1; d < 64; d <<= 1) s += __shfl_xor(s, d, 64);
    if (lane == 0) ush[l] = s + vbs;
  }
  __syncthreads();
  if (wv == 0) {
    float m = -3.4e38f; int idx = 0;
#pragma unroll
    for (int r = 0; r < 4; ++r) {                 // ascending l within lane
      const int l = lane * 4 + r;
      const float uu = ush[l];
      if (uu > m) { m = uu; idx = l; }
    }
#pragma unroll
    for (int d = 1; d < 64; d <<= 1) {            // tie -> smaller index (first occurrence)
      const float om = __shfl_xor(m, d, 64);
      const int   oi = __shfl_xor(idx, d, 64);
      if (om > m || (om == m && oi < idx)) { m = om; idx = oi; }
    }
    float se = 0.f;
#pragma unroll
    for (int r = 0; r < 4; ++r) se += __expf(ush[lane * 4 + r] - m);
#pragma unroll
    for (int d = 1; d < 64; d <<= 1) se += __shfl_xor(se, d, 64);
    if (lane == 0) { red[0] = m; red[1] = logf(se); pidx = idx; }
  }
  __syncthreads();
  if (tid == 0) {
    out_ptr[(size_t)b * NL + t] = (float)pidx;
    nxt[b] = in_seq[(size_t)b * NL + pidx];   // F=1
  }
  const float a = ush[tid] - red[0] - red[1];
  out_attn[((size_t)b * NL + t) * NL + tid] = a;
}

extern "C" void kernel_launch(void* const* d_in, const int* in_sizes, int n_in,
                              void* d_out, int out_size, void* d_ws, size_t ws_size,
                              hipStream_t stream) {
  const float* in_seq   = (const float*)d_in[0];
  const float* enc_embW = (const float*)d_in[1];
  const float* enc_embB = (const float*)d_in[2];
  const float* enc_Wih  = (const float*)d_in[3];
  const float* enc_Whh  = (const float*)d_in[4];
  const float* enc_bih  = (const float*)d_in[5];
  const float* enc_bhh  = (const float*)d_in[6];
  const float* dec_embW = (const float*)d_in[7];
  const float* dec_embB = (const float*)d_in[8];
  const float* dec_Wih  = (const float*)d_in[9];
  const float* dec_Whh  = (const float*)d_in[10];
  const float* dec_bih  = (const float*)d_in[11];
  const float* dec_bhh  = (const float*)d_in[12];
  const float* W1_W     = (const float*)d_in[13];
  const float* W1_b     = (const float*)d_in[14];
  const float* W2_W     = (const float*)d_in[15];
  const float* W2_b     = (const float*)d_in[16];
  const float* v_W      = (const float*)d_in[17];
  const float* v_b      = (const float*)d_in[18];

  float* wsf = (float*)d_ws;
  float* out_attn = (float*)d_out;
  float* out_ptr  = out_attn + (size_t)NB * NL * NL;

  // ---- prep: transposes, A/D folds, state init ----
  hipMemsetAsync(wsf + HPING, 0, (size_t)NB * NH * 4, stream);
  hipMemsetAsync(wsf + CBUF,  0, (size_t)NB * NH * 4, stream);
  k_init_nxt<<<1, NB, 0, stream>>>(wsf + NXT_OFF);

  k_transpose<<<(NG * NH + 255) / 256, 256, 0, stream>>>(enc_Whh, wsf + WT_ENC, NG, NH, 11);
  k_transpose<<<(NG * NH + 255) / 256, 256, 0, stream>>>(dec_Whh, wsf + WT_DEC, NG, NH, 11);
  k_transpose<<<(NH * NH + 255) / 256, 256, 0, stream>>>(W1_W, wsf + W1T_OFF, NH, NH, 9);
  k_transpose<<<(NH * NH + 255) / 256, 256, 0, stream>>>(W2_W, wsf + W2T_OFF, NH, NH, 9);

  k_prep_ad<<<512, 256, 0, stream>>>(enc_Wih, enc_embW, enc_embB, enc_bih, enc_bhh,
                                     wsf + A_ENC, wsf + D_ENC);
  k_prep_ad<<<512, 256, 0, stream>>>(dec_Wih, dec_embW, dec_embB, dec_bih, dec_bhh,
                                     wsf + A_DEC, wsf + D_DEC);

  // ---- encoder: 256 sequential LSTM steps; ep[t] fused in (no enc_out buffer) ----
  for (int t = 0; t < NL; ++t) {
    float* hsrc = wsf + ((t & 1) ? HPONG : HPING);
    float* hdst = wsf + ((t & 1) ? HPING : HPONG);
    k_gemm_part<<<dim3(32, 8, 4), 64, 0, stream>>>(hsrc, wsf + WT_ENC, wsf + PG_OFF, NG);
    k_lstm_post<<<dim3(2, NB), 256, 0, stream>>>(wsf + PG_OFF, wsf + A_ENC, wsf + D_ENC,
                                                 in_seq + t, NL, wsf + CBUF, hdst);
    // ep[t] = h_t @ W1^T + b1
    k_gemm_part<<<dim3(8, 8, 4), 64, 0, stream>>>(hdst, wsf + W1T_OFF, wsf + PQ_OFF, NH);
    k_ep_reduce<<<NB, 256, 0, stream>>>(wsf + PQ_OFF, W1_b,
                                        wsf + EP_OFF + (size_t)t * NB * NH);
  }

  // ---- decoder: 256 sequential steps (LSTM -> q -> attention/argmax) ----
  for (int t = 0; t < NL; ++t) {
    float* hsrc = wsf + ((t & 1) ? HPONG : HPING);
    float* hdst = wsf + ((t & 1) ? HPING : HPONG);
    k_gemm_part<<<dim3(32, 8, 4), 64, 0, stream>>>(hsrc, wsf + WT_DEC, wsf + PG_OFF, NG);
    k_lstm_post<<<dim3(2, NB), 256, 0, stream>>>(wsf + PG_OFF, wsf + A_DEC, wsf + D_DEC,
                                                 wsf + NXT_OFF, 1, wsf + CBUF, hdst);
    k_gemm_part<<<dim3(8, 8, 4), 64, 0, stream>>>(hdst, wsf + W2T_OFF, wsf + PQ_OFF, NH);
    k_attn<<<NB, 256, 0, stream>>>(wsf + PQ_OFF, W2_b, wsf + EP_OFF, v_W, v_b, in_seq,
                                   out_attn, out_ptr, wsf + NXT_OFF, t);
  }
}